// Round 3
// baseline (295.703 us; speedup 1.0000x reference)
//
#include <hip/hip_runtime.h>

#define TT 4096
#define BLK 256
#define PER 16     // TT / BLK
#define TPB 8      // traces per block; grid = 8192/8 = 1024 = 4 blocks/CU, fully resident
#define EPSV 1e-8f

// Async global->LDS, 16 bytes per lane. LDS dest is wave-uniform base + lane*16
// (HW rule); global src is per-lane. Destination layout must be linear.
__device__ __forceinline__ void async_q16(const float* __restrict__ g, float* l) {
  __builtin_amdgcn_global_load_lds(
      (const __attribute__((address_space(1))) void*)g,
      (__attribute__((address_space(3))) void*)l,
      16, 0, 0);
}

__global__ __launch_bounds__(BLK, 4) void w2_loss_kernel(
    const float* __restrict__ traces,
    const float* __restrict__ q_raw,
    float* __restrict__ part) {
  __shared__ float qb[2][TT];     // double-buffered q stage (32 KB)
  __shared__ float wave_sums[4];
  __shared__ float wave_red[4];

  const int tid = threadIdx.x;
  const int wv = tid >> 6;
  const int lane = tid & 63;
  const long trace0 = (long)blockIdx.x * TPB;
  const int base = tid * PER;

  // ---- Prologue: issue trace-0 q staging (async) + trace-0 register loads ----
  {
    const float* qr = q_raw + trace0 * (long)TT;
#pragma unroll
    for (int j = 0; j < 4; ++j) {
      const int c = (wv * 4 + j) * 256;           // 256-float chunk
      async_q16(qr + c + lane * 4, &qb[0][c]);    // lds base wave-uniform
    }
  }
  float4 trv[4];
  float nb;
  {
    const float* tr = traces + trace0 * (long)TT;
    const float4* tr4 = (const float4*)(tr + base);
#pragma unroll
    for (int j = 0; j < 4; ++j) trv[j] = tr4[j];
    nb = (base + PER < TT) ? tr[base + PER] : 0.0f;
  }

  for (int k = 0; k < TPB; ++k) {
    const int buf = k & 1;
    const long trace = trace0 + k;

    // ---- Phase 1: squares + per-thread cumtrapz (verbatim round 0) ----
    float s[PER + 1];
#pragma unroll
    for (int j = 0; j < 4; ++j) {
      s[4 * j + 0] = trv[j].x * trv[j].x + EPSV;
      s[4 * j + 1] = trv[j].y * trv[j].y + EPSV;
      s[4 * j + 2] = trv[j].z * trv[j].z + EPSV;
      s[4 * j + 3] = trv[j].w * trv[j].w + EPSV;
    }
    s[PER] = (base + PER < TT) ? (nb * nb + EPSV) : 0.0f;

    float lc[PER + 1];
    lc[0] = 0.0f;
#pragma unroll
    for (int m = 0; m < PER; ++m) {
      float t0 = (float)(base + m) * 1e-3f;
      float t1 = (float)(base + m + 1) * 1e-3f;
      float incr = (base + m < TT - 1) ? 0.5f * (s[m] + s[m + 1]) * (t1 - t0)
                                       : 0.0f;
      lc[m + 1] = lc[m] + incr;
    }
    const float tot = lc[PER];

    // Wave-level inclusive scan of thread totals (wave = 64 lanes).
    float v = tot;
#pragma unroll
    for (int off = 1; off < 64; off <<= 1) {
      float n = __shfl_up(v, off, 64);
      if (lane >= off) v += n;
    }
    if (lane == 63) wave_sums[wv] = v;
    __syncthreads();  // B1: wave_sums visible; qb[buf] staging long since landed

    // ---- Issue NEXT trace's loads now: they overlap gather+reduce below ----
    if (k + 1 < TPB) {
      const float* qr_n = q_raw + (trace + 1) * (long)TT;
#pragma unroll
      for (int j = 0; j < 4; ++j) {
        const int c = (wv * 4 + j) * 256;
        async_q16(qr_n + c + lane * 4, &qb[buf ^ 1][c]);
      }
      const float* tr_n = traces + (trace + 1) * (long)TT;
      const float4* tr4_n = (const float4*)(tr_n + base);
#pragma unroll
      for (int j = 0; j < 4; ++j) trv[j] = tr4_n[j];
      nb = (base + PER < TT) ? tr_n[base + PER] : 0.0f;
    }

    float wave_off = 0.0f;
    if (wv > 0) wave_off += wave_sums[0];
    if (wv > 1) wave_off += wave_sums[1];
    if (wv > 2) wave_off += wave_sums[2];
    const float excl = (v - tot) + wave_off;
    const float norm = wave_sums[0] + wave_sums[1] + wave_sums[2] + wave_sums[3];
    const float inv_norm = 1.0f / norm;

    // ---- Phase 2: cdf -> analytic-p interp -> loss (verbatim round 0) ----
    const float* __restrict__ lq = qb[buf];
    float local = 0.0f;
#pragma unroll
    for (int m = 0; m < PER; ++m) {
      float x = (excl + lc[m]) * inv_norm;       // cdf in [0,1]
      float u = x * (float)(TT - 1);             // analytic index on uniform p
      int i0 = (int)floorf(u);
      i0 = (i0 < 0) ? 0 : ((i0 > TT - 2) ? TT - 2 : i0);
      float f = u - (float)i0;
      f = fminf(fmaxf(f, 0.0f), 1.0f);           // jnp.interp endpoint clamp
      float q0 = lq[i0];
      float q1 = lq[i0 + 1];
      float transport = q0 + f * (q1 - q0);
      float tm = (float)(base + m) * 1e-3f;
      float d = tm - transport;
      float tlo = (float)((base + m == 0) ? 0 : (base + m - 1)) * 1e-3f;
      float thi = (float)((base + m == TT - 1) ? (TT - 1) : (base + m + 1)) * 1e-3f;
      float w = 0.5f * (thi - tlo);              // collapsed trapz weight
      local += d * d * s[m] * w;
    }
    local *= inv_norm;

    // ---- Block reduce, one coalesced store per trace ----
#pragma unroll
    for (int off = 32; off > 0; off >>= 1) local += __shfl_down(local, off, 64);
    if (lane == 0) wave_red[wv] = local;
    __syncthreads();  // B2: wave_red visible; drains next-trace loads (overlapped)
    if (tid == 0) {
      part[trace] = wave_red[0] + wave_red[1] + wave_red[2] + wave_red[3];
    }
    // wave_sums(k+1) written after scan(k+1), which is after B2 -> race-free.
  }
}

__global__ __launch_bounds__(BLK) void reduce_kernel(
    const float* __restrict__ part, float* __restrict__ out, int n) {
  __shared__ float wave_red[4];
  const int tid = threadIdx.x;
  float local = 0.0f;
  for (int i = tid; i < n; i += BLK) local += part[i];
#pragma unroll
  for (int off = 32; off > 0; off >>= 1) local += __shfl_down(local, off, 64);
  if ((tid & 63) == 0) wave_red[tid >> 6] = local;
  __syncthreads();
  if (tid == 0) out[0] = wave_red[0] + wave_red[1] + wave_red[2] + wave_red[3];
}

extern "C" void kernel_launch(void* const* d_in, const int* in_sizes, int n_in,
                              void* d_out, int out_size, void* d_ws, size_t ws_size,
                              hipStream_t stream) {
  const float* traces = (const float*)d_in[0];
  const float* q_raw  = (const float*)d_in[3];
  float* out = (float*)d_out;
  float* part = (float*)d_ws;  // 8192 floats = 32 KB scratch

  const int n_traces = in_sizes[0] / TT;   // B*R = 8192
  const int n_blocks = n_traces / TPB;     // 1024 = 4 blocks/CU, fully resident
  w2_loss_kernel<<<n_blocks, BLK, 0, stream>>>(traces, q_raw, part);
  reduce_kernel<<<1, BLK, 0, stream>>>(part, out, n_traces);
}